// Round 15
// baseline (3118.669 us; speedup 1.0000x reference)
//
#include <hip/hip_runtime.h>
#include <stdint.h>

// ---------------------------------------------------------------------------
// LSTM time-series predictor, persistent kernel, R17.
// Base = R14 (verified 2756/2762us, reproduced twice; session best).
// TRANSPORT (settled R8b/R10/R11): device/agent scope (MALL) is the only
// coherent cross-CU path on gfx950. Exchange = R9b-verified tag protocol:
// |h|<1 -> bf16 bit14==0 -> 2-bit epoch tag q=(e>>1)&3 in both dwords of
// each packed u64; consumers poll the data itself. 2 slots/queue, poison
// 0xFF, guard 8192. Publish-early ordering (R12). Batched sc1 loads (R14).
// R17 CHANGE (poll bodies only): SENTINEL polling. FETCH_SIZE=96MB showed
// the polls re-fetch the full 16KB queues through TCC every failed
// iteration (x2048 waves at s_sleep(1) cadence -> coherence-point
// contention is the candidate for the unexplained 2x in the 9400cy/step
// budget). Each thread now spins on ONE sentinel entry (1 load vs 4/8);
// only on sentinel tag-match does it issue the full batched load + the
// UNCHANGED full per-entry check before staging (correctness identical).
// Poll traffic -4..8x; success path +<=1 RTT. Outcomes pre-registered:
// contention-real -> ~2300-2600us & FETCH ~30-50MB; latency-only ->
// ~2800-3050us regression (revert to R14 and declare floor).
// Epochs: h0: enc t=0..511, dec 512+d. h1: enc t-1 at step t, dec 512+d.
// slot = e&1, tag = (e>>1)&3.
// ---------------------------------------------------------------------------

#define NWG 256
#define NTH 256

constexpr int Tt = 512, TGT = 96;

typedef __attribute__((ext_vector_type(8))) short bf16x8;
typedef __attribute__((ext_vector_type(4))) float f32x4;
typedef unsigned long long u64;

#define TAGBITS 0x4000400040004000ULL

__device__ __forceinline__ unsigned short f2bf(float f) {
  union { float f; unsigned u; } v; v.f = f;
  return (unsigned short)((v.u + 0x7fffu + ((v.u >> 16) & 1u)) >> 16);
}
__device__ __forceinline__ float bf2f(unsigned short h) {
  union { unsigned u; float f; } v; v.u = ((unsigned)h) << 16; return v.f;
}
__device__ __forceinline__ float sigm(float x) { return 1.f / (1.f + __expf(-x)); }
__device__ __forceinline__ float tanh_(float x) { return 1.f - 2.f / (__expf(2.f * x) + 1.f); }

__device__ __forceinline__ void ast64a(u64* p, u64 v) {
  __hip_atomic_store(p, v, __ATOMIC_RELAXED, __HIP_MEMORY_SCOPE_AGENT);
}

// epoch tag mask: q=(e>>1)&3; q bit0 -> bf16 lanes 0,2 (bits 14,46),
// q bit1 -> lanes 1,3 (bits 30,62). Replicated per dword -> torn-view safe.
__device__ __forceinline__ u64 tmask(int e) {
  int q = (e >> 1) & 3;
  return (u64)(q & 1) * 0x0000400000004000ULL
       | (u64)((q >> 1) & 1) * 0x4000000040000000ULL;
}

struct SMem {
  unsigned short wB[2][4][16][64][8]; // 128 KiB: [whh0|wih1][wave][kc][lane][8]
  u64 a0[16 * 68];                    // 8.5 KiB staged A: [kc][b*8 + k8&7]
  u64 a1[16 * 68];                    // 8.5 KiB
  unsigned short wfc2[1024];          // 2 KiB: W_fc rows w*2, w*2+1 (bf16)
  float gpart[4][272];                // per-wave D staging
  float fcp[256];                     // fc partials
  float b0s[64], b1s[64], b0d[64], bfc2[2];
};                                    // ~153 KiB

// staged-A LDS u64 index for global h u64-index idx (b=idx>>7, k8=idx&127)
__device__ __forceinline__ int amap(int idx) {
  int b = idx >> 7, k8 = idx & 127;
  return (k8 >> 3) * 68 + b * 8 + (k8 & 7);
}

// poll-stage with SENTINEL: spin on ONE tagged entry; on match, do the full
// batched device-scope load + full per-entry check (consumption gate
// unchanged). Rule #18: vmcnt + sched_barrier after each asm batch.
__device__ __forceinline__ void pollstage1(u64* dst, const u64* src, u64 want, int tid) {
  u64 v0, v1, v2, v3;
  const u64* p0 = src + tid;       const u64* p1 = src + tid + 256;
  const u64* p2 = src + tid + 512; const u64* p3 = src + tid + 768;
  int guard = 0;
  while (true) {
    u64 s;
    asm volatile("global_load_dwordx2 %0, %1, off sc1\n\ts_waitcnt vmcnt(0)"
                 : "=&v"(s) : "v"(p0) : "memory");
    __builtin_amdgcn_sched_barrier(0);
    bool sok = ((s & TAGBITS) == want);
    ++guard;
    if (sok || guard > 8192) {
      asm volatile(
        "global_load_dwordx2 %0, %4, off sc1\n\t"
        "global_load_dwordx2 %1, %5, off sc1\n\t"
        "global_load_dwordx2 %2, %6, off sc1\n\t"
        "global_load_dwordx2 %3, %7, off sc1\n\t"
        "s_waitcnt vmcnt(0)"
        : "=&v"(v0), "=&v"(v1), "=&v"(v2), "=&v"(v3)
        : "v"(p0), "v"(p1), "v"(p2), "v"(p3)
        : "memory");
      __builtin_amdgcn_sched_barrier(0);
      bool ok = ((v0 & TAGBITS) == want) & ((v1 & TAGBITS) == want) &
                ((v2 & TAGBITS) == want) & ((v3 & TAGBITS) == want);
      if (ok || guard > 8192) break;
    }
    __builtin_amdgcn_s_sleep(1);
  }
  dst[amap(tid)]       = v0 & ~TAGBITS; dst[amap(tid + 256)] = v1 & ~TAGBITS;
  dst[amap(tid + 512)] = v2 & ~TAGBITS; dst[amap(tid + 768)] = v3 & ~TAGBITS;
}
__device__ __forceinline__ void pollstage2(u64* d0, const u64* s0, u64 w0,
                                           u64* d1, const u64* s1, u64 w1, int tid) {
  u64 a0, a1, a2, a3, b0, b1, b2, b3;
  const u64* pa0 = s0 + tid;       const u64* pa1 = s0 + tid + 256;
  const u64* pa2 = s0 + tid + 512; const u64* pa3 = s0 + tid + 768;
  const u64* pb0 = s1 + tid;       const u64* pb1 = s1 + tid + 256;
  const u64* pb2 = s1 + tid + 512; const u64* pb3 = s1 + tid + 768;
  int guard = 0;
  while (true) {
    u64 sa, sb;
    asm volatile(
      "global_load_dwordx2 %0, %2, off sc1\n\t"
      "global_load_dwordx2 %1, %3, off sc1\n\t"
      "s_waitcnt vmcnt(0)"
      : "=&v"(sa), "=&v"(sb) : "v"(pa0), "v"(pb0) : "memory");
    __builtin_amdgcn_sched_barrier(0);
    bool sok = ((sa & TAGBITS) == w0) & ((sb & TAGBITS) == w1);
    ++guard;
    if (sok || guard > 8192) {
      asm volatile(
        "global_load_dwordx2 %0, %8, off sc1\n\t"
        "global_load_dwordx2 %1, %9, off sc1\n\t"
        "global_load_dwordx2 %2, %10, off sc1\n\t"
        "global_load_dwordx2 %3, %11, off sc1\n\t"
        "global_load_dwordx2 %4, %12, off sc1\n\t"
        "global_load_dwordx2 %5, %13, off sc1\n\t"
        "global_load_dwordx2 %6, %14, off sc1\n\t"
        "global_load_dwordx2 %7, %15, off sc1\n\t"
        "s_waitcnt vmcnt(0)"
        : "=&v"(a0), "=&v"(a1), "=&v"(a2), "=&v"(a3),
          "=&v"(b0), "=&v"(b1), "=&v"(b2), "=&v"(b3)
        : "v"(pa0), "v"(pa1), "v"(pa2), "v"(pa3),
          "v"(pb0), "v"(pb1), "v"(pb2), "v"(pb3)
        : "memory");
      __builtin_amdgcn_sched_barrier(0);
      bool ok = ((a0 & TAGBITS) == w0) & ((a1 & TAGBITS) == w0) &
                ((a2 & TAGBITS) == w0) & ((a3 & TAGBITS) == w0) &
                ((b0 & TAGBITS) == w1) & ((b1 & TAGBITS) == w1) &
                ((b2 & TAGBITS) == w1) & ((b3 & TAGBITS) == w1);
      if (ok || guard > 8192) break;
    }
    __builtin_amdgcn_s_sleep(1);
  }
  d0[amap(tid)]       = a0 & ~TAGBITS; d0[amap(tid + 256)] = a1 & ~TAGBITS;
  d0[amap(tid + 512)] = a2 & ~TAGBITS; d0[amap(tid + 768)] = a3 & ~TAGBITS;
  d1[amap(tid)]       = b0 & ~TAGBITS; d1[amap(tid + 256)] = b1 & ~TAGBITS;
  d1[amap(tid + 512)] = b2 & ~TAGBITS; d1[amap(tid + 768)] = b3 & ~TAGBITS;
}

#define MFMA(a, b, c) __builtin_amdgcn_mfma_f32_16x16x32_bf16(a, b, c, 0, 0, 0)

__global__ __launch_bounds__(NTH, 1) void lstm_kernel(
    const float* __restrict__ x,
    const float* __restrict__ Wih0, const float* __restrict__ Whh0,
    const float* __restrict__ bih0, const float* __restrict__ bhh0,
    const float* __restrict__ Wih1, const float* __restrict__ Whh1,
    const float* __restrict__ bih1, const float* __restrict__ bhh1,
    const float* __restrict__ Wfc, const float* __restrict__ bfc,
    u64* h0q, u64* h1q, float* __restrict__ out)
{
  __shared__ SMem sm;
  const int g = blockIdx.x & 7;
  const int wgw = blockIdx.x >> 3;
  const int tid = threadIdx.x;

  // ---- weight staging (fragment-major, conflict-free reads) ----
  for (int e = tid; e < 8192; e += NTH) {   // 2 mats x 4 waves x 16 kc x 64 lanes
    int m = e >> 12, w4 = (e >> 10) & 3, kc = (e >> 6) & 15, l = e & 63;
    int colx = l & 15, qx = l >> 4;
    size_t row = (size_t)((colx & 3) * 512 + wgw * 16 + w4 * 4 + (colx >> 2));
    const float* src = (m ? Wih1 : Whh0) + row * 512 + kc * 32 + qx * 8;
    unsigned short* dst = &sm.wB[m][w4][kc][l][0];
    float4 u = *(const float4*)src, v = *(const float4*)(src + 4);
    dst[0] = f2bf(u.x); dst[1] = f2bf(u.y); dst[2] = f2bf(u.z); dst[3] = f2bf(u.w);
    dst[4] = f2bf(v.x); dst[5] = f2bf(v.y); dst[6] = f2bf(v.z); dst[7] = f2bf(v.w);
  }
  for (int e = tid; e < 1024; e += NTH)
    sm.wfc2[e] = f2bf(Wfc[(size_t)(wgw * 2 + (e >> 9)) * 512 + (e & 511)]);
  if (tid < 64) {
    int jj = tid >> 2, g4 = tid & 3;
    int grow = g4 * 512 + wgw * 16 + jj;
    float s0 = bih0[grow] + bhh0[grow];
    sm.b0s[tid] = s0;
    sm.b1s[tid] = bih1[grow] + bhh1[grow];
    float ex = 0.f;                         // Wih0 row dot bfc (decoder bias)
    for (int i = 0; i < 64; ++i) ex += Wih0[(size_t)grow * 64 + i] * bfc[i];
    sm.b0d[tid] = s0 + ex;
  }
  if (tid < 2) sm.bfc2[tid] = bfc[wgw * 2 + tid];

  // ---- per-lane constants ----
  const int wave = tid >> 6, lane = tid & 63;
  const int col = lane & 15, quad = lane >> 4;
  const int koff = quad * 8;
  const size_t rowg = (size_t)((col & 3) * 512 + wgw * 16 + wave * 4 + (col >> 2));

  // ---- register B-fragments: W_hh1, W_ih0, Wcomb = Wih0 @ Wfc ----
  bf16x8 whh1f[16];
#pragma unroll
  for (int kc = 0; kc < 16; ++kc) {
    const float* p = Whh1 + rowg * 512 + kc * 32 + koff;
    float4 u = *(const float4*)p, v = *(const float4*)(p + 4);
    bf16x8 r;
    r[0] = (short)f2bf(u.x); r[1] = (short)f2bf(u.y); r[2] = (short)f2bf(u.z); r[3] = (short)f2bf(u.w);
    r[4] = (short)f2bf(v.x); r[5] = (short)f2bf(v.y); r[6] = (short)f2bf(v.z); r[7] = (short)f2bf(v.w);
    whh1f[kc] = r;
  }
  bf16x8 wih0f[2];
#pragma unroll
  for (int kc = 0; kc < 2; ++kc) {
    const float* p = Wih0 + rowg * 64 + kc * 32 + koff;
    float4 u = *(const float4*)p, v = *(const float4*)(p + 4);
    bf16x8 r;
    r[0] = (short)f2bf(u.x); r[1] = (short)f2bf(u.y); r[2] = (short)f2bf(u.z); r[3] = (short)f2bf(u.w);
    r[4] = (short)f2bf(v.x); r[5] = (short)f2bf(v.y); r[6] = (short)f2bf(v.z); r[7] = (short)f2bf(v.w);
    wih0f[kc] = r;
  }
  bf16x8 wcombf[16];
  {
    float wc[16][8];
#pragma unroll
    for (int kc = 0; kc < 16; ++kc)
#pragma unroll
      for (int j = 0; j < 8; ++j) wc[kc][j] = 0.f;
    for (int i = 0; i < 64; ++i) {
      float wi = Wih0[rowg * 64 + i];
      const float* fr = Wfc + (size_t)i * 512 + koff;
#pragma unroll
      for (int kc = 0; kc < 16; ++kc) {
        float4 u = *(const float4*)(fr + kc * 32);
        float4 v = *(const float4*)(fr + kc * 32 + 4);
        wc[kc][0] += wi * u.x; wc[kc][1] += wi * u.y;
        wc[kc][2] += wi * u.z; wc[kc][3] += wi * u.w;
        wc[kc][4] += wi * v.x; wc[kc][5] += wi * v.y;
        wc[kc][6] += wi * v.z; wc[kc][7] += wi * v.w;
      }
    }
#pragma unroll
    for (int kc = 0; kc < 16; ++kc) {
      bf16x8 r;
#pragma unroll
      for (int j = 0; j < 8; ++j) r[j] = (short)f2bf(wc[kc][j]);
      wcombf[kc] = r;
    }
  }
  __syncthreads();

  const float b0c = sm.b0s[wave * 16 + col];
  const float b1c = sm.b1s[wave * 16 + col];
  const float b0dc = sm.b0d[wave * 16 + col];
  const unsigned short* pw0 = &sm.wB[0][wave][0][lane][0];   // + kc*512 ushort
  const unsigned short* pw1 = &sm.wB[1][wave][0][lane][0];
  const u64* afrag0 = sm.a0 + (col & 7) * 8 + quad * 2;      // + kc*68
  const u64* afrag1 = sm.a1 + (col & 7) * 8 + quad * 2;
  float c0 = 0.f, c1 = 0.f;
  const size_t xstride = (size_t)Tt * 64;

  auto hslot = [&](u64* hq, int e) -> u64* {
    return hq + ((size_t)(e & 1) << 13) + g * 1024;
  };

  auto loadx = [&](const float* p) -> bf16x8 {
    float4 u = *(const float4*)p, v = *(const float4*)(p + 4);
    bf16x8 r;
    r[0] = (short)f2bf(u.x); r[1] = (short)f2bf(u.y); r[2] = (short)f2bf(u.z); r[3] = (short)f2bf(u.w);
    r[4] = (short)f2bf(v.x); r[5] = (short)f2bf(v.y); r[6] = (short)f2bf(v.z); r[7] = (short)f2bf(v.w);
    return r;
  };

  // compute h, publish TAGGED to the epoch slot (agent store, fire-and-forget)
  auto actstore = [&](f32x4 v, float& cst, u64* hdst, u64 tg) {
    float* gp = sm.gpart[wave];
#pragma unroll
    for (int r = 0; r < 4; ++r) gp[(quad * 4 + r) * 17 + col] = v[r];
    unsigned hbits = 0;
    int b = lane >> 2, j = lane & 3;
    if (lane < 32) {
      const float* ro = gp + b * 17 + j * 4;
      float iv = sigm(ro[0]), fv = sigm(ro[1]), gv = tanh_(ro[2]), ov = sigm(ro[3]);
      float c = fv * cst + iv * gv; cst = c;
      hbits = f2bf(ov * tanh_(c));   // |h|<1 -> bit14 == 0 guaranteed
    }
    unsigned h1b = __shfl(hbits, (lane + 1) & 63);
    unsigned h2b = __shfl(hbits, (lane + 2) & 63);
    unsigned h3b = __shfl(hbits, (lane + 3) & 63);
    if (lane < 32 && j == 0) {
      u64 pk = (u64)hbits | ((u64)h1b << 16) | ((u64)h2b << 32) | ((u64)h3b << 48);
      ast64a(hdst + b * 128 + wgw * 4 + wave, pk | tg);
    }
  };

  auto fcpart = [&](const u64* asrc) {      // fc partials from staged h1
    int ks = tid >> 4, b = (tid >> 1) & 7, cc = tid & 1;
    const unsigned short* hr = (const unsigned short*)(asrc + ks * 68 + b * 8);
    const unsigned short* wp = sm.wfc2 + cc * 512 + ks * 32;
    float s = 0.f;
#pragma unroll
    for (int k2 = 0; k2 < 4; ++k2) {
      bf16x8 hv = *(const bf16x8*)(hr + k2 * 8);
      bf16x8 wv = *(const bf16x8*)(wp + k2 * 8);
#pragma unroll
      for (int q2 = 0; q2 < 8; ++q2) s += bf2f((unsigned short)hv[q2]) * bf2f((unsigned short)wv[q2]);
    }
    sm.fcp[tid] = s;
  };
  auto fcout = [&](int d) {                 // reduce + write out[d] (tid<16)
    if (tid < 16) {
      float sv = sm.bfc2[tid & 1];
#pragma unroll
      for (int k = 0; k < 16; ++k) sv += sm.fcp[k * 16 + tid];
      int bb = tid >> 1, cc = tid & 1;
      out[(size_t)(g * 8 + bb) * (TGT * 64) + d * 64 + (wgw * 2 + cc)] = sv;
    }
  };

  // ================= encoder: t = 0..512, layer1 lags by 1 =================
  for (int t = 0; t <= Tt; ++t) {
    bf16x8 xa0, xa1;
    if (t < Tt) {
      const float* xb = x + (size_t)(g * 8 + (col & 7)) * xstride + (size_t)t * 64 + koff;
      xa0 = loadx(xb); xa1 = loadx(xb + 32);
    }
    if (t == 1) {
      __syncthreads();                     // prior-step LDS readers done
      pollstage1(sm.a0, hslot(h0q, 0), tmask(0), tid);
      __syncthreads();
    } else if (t >= 2) {
      __syncthreads();
      pollstage2(sm.a0, hslot(h0q, t - 1), tmask(t - 1),
                 sm.a1, hslot(h1q, t - 2), tmask(t - 2), tid);
      __syncthreads();
    }

    if (t < Tt) {
      f32x4 za = {b0c, b0c, b0c, b0c}, zb = {0.f, 0.f, 0.f, 0.f};
      za = MFMA(xa0, wih0f[0], za);
      zb = MFMA(xa1, wih0f[1], zb);
      if (t >= 1) {
        // ---- layer0 FIRST (the h0 chain), publish h0 EARLY (R12) ----
#pragma unroll
        for (int kc = 0; kc < 16; ++kc) {
          bf16x8 a = *(const bf16x8*)(afrag0 + kc * 68);
          bf16x8 w0 = *(const bf16x8*)(pw0 + kc * 512);
          if (kc & 1) zb = MFMA(a, w0, zb);
          else        za = MFMA(a, w0, za);
        }
        actstore(za + zb, c0, hslot(h0q, t), tmask(t));
        // ---- layer1 second (consumed one phase later; off the h0 chain) --
        f32x4 ya = {b1c, b1c, b1c, b1c}, yb = {0.f, 0.f, 0.f, 0.f};
#pragma unroll
        for (int kc = 0; kc < 16; ++kc) {
          bf16x8 a = *(const bf16x8*)(afrag0 + kc * 68);
          bf16x8 w1 = *(const bf16x8*)(pw1 + kc * 512);
          if (kc & 1) yb = MFMA(a, w1, yb);
          else        ya = MFMA(a, w1, ya);
        }
        if (t >= 2) {
#pragma unroll
          for (int kc = 0; kc < 16; ++kc) {
            bf16x8 a = *(const bf16x8*)(afrag1 + kc * 68);
            if (kc & 1) yb = MFMA(a, whh1f[kc], yb);
            else        ya = MFMA(a, whh1f[kc], ya);
          }
        }
        actstore(ya + yb, c1, hslot(h1q, t - 1), tmask(t - 1));
      } else {
        actstore(za + zb, c0, hslot(h0q, 0), tmask(0));
      }
    } else {                                   // t == Tt: final layer1 step
      f32x4 ya = {b1c, b1c, b1c, b1c}, yb = {0.f, 0.f, 0.f, 0.f};
#pragma unroll
      for (int kc = 0; kc < 16; ++kc) {
        bf16x8 a = *(const bf16x8*)(afrag0 + kc * 68);
        bf16x8 w1 = *(const bf16x8*)(pw1 + kc * 512);
        if (kc & 1) yb = MFMA(a, w1, yb);
        else        ya = MFMA(a, w1, ya);
      }
#pragma unroll
      for (int kc = 0; kc < 16; ++kc) {
        bf16x8 a = *(const bf16x8*)(afrag1 + kc * 68);
        if (kc & 1) yb = MFMA(a, whh1f[kc], yb);
        else        ya = MFMA(a, whh1f[kc], ya);
      }
      actstore(ya + yb, c1, hslot(h1q, Tt - 1), tmask(Tt - 1));
    }
  }

  // ================= decoder (h0 epochs 512+d, h1 epochs 512+d) ============
  // d=0, phase A (real x input):
  {
    __syncthreads();
    pollstage2(sm.a0, hslot(h0q, 511), tmask(511),
               sm.a1, hslot(h1q, 511), tmask(511), tid);
    __syncthreads();
    const float* xb = x + (size_t)(g * 8 + (col & 7)) * xstride + (size_t)(Tt - 1) * 64 + koff;
    bf16x8 xa0 = loadx(xb), xa1 = loadx(xb + 32);
    f32x4 za = {b0c, b0c, b0c, b0c}, zb = {0.f, 0.f, 0.f, 0.f};
    za = MFMA(xa0, wih0f[0], za);
    zb = MFMA(xa1, wih0f[1], zb);
#pragma unroll
    for (int kc = 0; kc < 16; ++kc) {
      bf16x8 a = *(const bf16x8*)(afrag0 + kc * 68);
      bf16x8 w0 = *(const bf16x8*)(pw0 + kc * 512);
      if (kc & 1) zb = MFMA(a, w0, zb);
      else        za = MFMA(a, w0, za);
    }
    actstore(za + zb, c0, hslot(h0q, 512), tmask(512));
  }
  // d=0, phase B (a1 still holds h1_enc_last = epoch 511):
  {
    __syncthreads();
    pollstage1(sm.a0, hslot(h0q, 512), tmask(512), tid);
    __syncthreads();
    f32x4 ya = {b1c, b1c, b1c, b1c}, yb = {0.f, 0.f, 0.f, 0.f};
#pragma unroll
    for (int kc = 0; kc < 16; ++kc) {
      bf16x8 a = *(const bf16x8*)(afrag0 + kc * 68);
      bf16x8 w1 = *(const bf16x8*)(pw1 + kc * 512);
      bf16x8 a2 = *(const bf16x8*)(afrag1 + kc * 68);
      if (kc & 1) { yb = MFMA(a, w1, yb); yb = MFMA(a2, whh1f[kc], yb); }
      else        { ya = MFMA(a, w1, ya); ya = MFMA(a2, whh1f[kc], ya); }
    }
    actstore(ya + yb, c1, hslot(h1q, 512), tmask(512));
  }

  for (int d = 1; d < TGT; ++d) {
    // phase A': layer0 with folded fc feedback (Wcomb); gates+publish FIRST,
    // fc epilogue (out[d-1]) after — off the h0 chain (R12).
    {
      __syncthreads();
      pollstage2(sm.a0, hslot(h0q, 511 + d), tmask(511 + d),
                 sm.a1, hslot(h1q, 511 + d), tmask(511 + d), tid);
      __syncthreads();
      f32x4 za = {b0dc, b0dc, b0dc, b0dc}, zb = {0.f, 0.f, 0.f, 0.f};
#pragma unroll
      for (int kc = 0; kc < 16; ++kc) {
        bf16x8 a = *(const bf16x8*)(afrag0 + kc * 68);
        bf16x8 w0 = *(const bf16x8*)(pw0 + kc * 512);
        bf16x8 a2 = *(const bf16x8*)(afrag1 + kc * 68);
        if (kc & 1) { zb = MFMA(a, w0, zb); zb = MFMA(a2, wcombf[kc], zb); }
        else        { za = MFMA(a, w0, za); za = MFMA(a2, wcombf[kc], za); }
      }
      actstore(za + zb, c0, hslot(h0q, 512 + d), tmask(512 + d));
      fcpart(sm.a1);                                 // y_{d-1} partials (epilogue)
      __syncthreads();
      fcout(d - 1);
    }
    // phase B: layer1 (a1 still holds h1_{d-1})
    {
      __syncthreads();
      pollstage1(sm.a0, hslot(h0q, 512 + d), tmask(512 + d), tid);
      __syncthreads();
      f32x4 ya = {b1c, b1c, b1c, b1c}, yb = {0.f, 0.f, 0.f, 0.f};
#pragma unroll
      for (int kc = 0; kc < 16; ++kc) {
        bf16x8 a = *(const bf16x8*)(afrag0 + kc * 68);
        bf16x8 w1 = *(const bf16x8*)(pw1 + kc * 512);
        bf16x8 a2 = *(const bf16x8*)(afrag1 + kc * 68);
        if (kc & 1) { yb = MFMA(a, w1, yb); yb = MFMA(a2, whh1f[kc], yb); }
        else        { ya = MFMA(a, w1, ya); ya = MFMA(a2, whh1f[kc], ya); }
      }
      actstore(ya + yb, c1, hslot(h1q, 512 + d), tmask(512 + d));
    }
  }

  // final fc: out[95] from h1 epoch 607
  {
    __syncthreads();
    pollstage1(sm.a1, hslot(h1q, 512 + TGT - 1), tmask(512 + TGT - 1), tid);
    __syncthreads();
    fcpart(sm.a1);
    __syncthreads();
    fcout(TGT - 1);
  }
}

extern "C" void kernel_launch(void* const* d_in, const int* in_sizes, int n_in,
                              void* d_out, int out_size, void* d_ws, size_t ws_size,
                              hipStream_t stream) {
  (void)in_sizes; (void)n_in; (void)out_size; (void)ws_size;
  const float* x    = (const float*)d_in[0];
  const float* Wih0 = (const float*)d_in[1];
  const float* Whh0 = (const float*)d_in[2];
  const float* bih0 = (const float*)d_in[3];
  const float* bhh0 = (const float*)d_in[4];
  const float* Wih1 = (const float*)d_in[5];
  const float* Whh1 = (const float*)d_in[6];
  const float* bih1 = (const float*)d_in[7];
  const float* bhh1 = (const float*)d_in[8];
  const float* Wfc  = (const float*)d_in[9];
  const float* bfc  = (const float*)d_in[10];

  char* ws = (char*)d_ws;
  u64* h0q = (u64*)ws;                    // 2 slots x 8192 u64 = 128 KiB
  u64* h1q = (u64*)(ws + 131072);         // 128 KiB

  // 0xFF poison: tag bits all 1 (q=3) -> mismatches the q=0 tags of epochs
  // 0/1, so never-written entries can't be consumed. Total ws use: 256 KiB.
  hipMemsetAsync(ws, 0xFF, 262144, stream);
  hipLaunchKernelGGL(lstm_kernel, dim3(NWG), dim3(NTH), 0, stream,
                     x, Wih0, Whh0, bih0, bhh0, Wih1, Whh1, bih1, bhh1, Wfc, bfc,
                     h0q, h1q, (float*)d_out);
}

// Round 16
// 2739.823 us; speedup vs baseline: 1.1383x; 1.1383x over previous
//
#include <hip/hip_runtime.h>
#include <stdint.h>

// ---------------------------------------------------------------------------
// LSTM time-series predictor, persistent kernel, FINAL == R14 (verified
// 2756/2762us, reproduced; session best, down from 2898us baseline).
// LEVER LEDGER (all hardware-measured this session):
//  +WIN  R12 publish-early (layer0+h0 publish before layer1): 2940->2765.
//  +WIN  R9 tag-in-data protocol (epoch tags in spare bf16 bit14 slots,
//        poll the data itself; no flag barrier). Equal speed to R7 flags but
//        simpler and enables publish-early wins.
//  =NEUT R14 batched sc1 poll loads (hipcc wasn't serializing).
//  -LOSS R15 split polls (h1 was never the binding wait -> added serial RTT).
//  -LOSS R17 sentinel polls (polls succeed in ~1 iter; added RTT, FETCH flat).
//  xDEAD intra-XCD L2 exchange family (R8b/R10/R11): plain/sc0/sc1 stores +
//        sc0 loads NOT producer->consumer coherent across CUs on gfx950,
//        under blockIdx- AND hardware-XCC_ID grouping. Agent scope (MALL)
//        is the only working transport.
// RESIDUAL: ~9400cy/step = 2 logical exchanges x publish->MALL->discover
// latency + max-of-32-WG skew. Latency floor: MfmaUtil 7.5%, HBM 1.8% --
// not a compute or bandwidth roofline; structural to the 705-step serial
// cross-WG dependency chain at device scope.
// Epochs: h0: enc t=0..511, dec 512+d. h1: enc t-1 at step t, dec 512+d.
// slot = e&1, tag = (e>>1)&3. Poison 0xFF; poll guard 8192 (no-hang).
// ---------------------------------------------------------------------------

#define NWG 256
#define NTH 256

constexpr int Tt = 512, TGT = 96;

typedef __attribute__((ext_vector_type(8))) short bf16x8;
typedef __attribute__((ext_vector_type(4))) float f32x4;
typedef unsigned long long u64;

#define TAGBITS 0x4000400040004000ULL

__device__ __forceinline__ unsigned short f2bf(float f) {
  union { float f; unsigned u; } v; v.f = f;
  return (unsigned short)((v.u + 0x7fffu + ((v.u >> 16) & 1u)) >> 16);
}
__device__ __forceinline__ float bf2f(unsigned short h) {
  union { unsigned u; float f; } v; v.u = ((unsigned)h) << 16; return v.f;
}
__device__ __forceinline__ float sigm(float x) { return 1.f / (1.f + __expf(-x)); }
__device__ __forceinline__ float tanh_(float x) { return 1.f - 2.f / (__expf(2.f * x) + 1.f); }

__device__ __forceinline__ void ast64a(u64* p, u64 v) {
  __hip_atomic_store(p, v, __ATOMIC_RELAXED, __HIP_MEMORY_SCOPE_AGENT);
}

// epoch tag mask: q=(e>>1)&3; q bit0 -> bf16 lanes 0,2 (bits 14,46),
// q bit1 -> lanes 1,3 (bits 30,62). Replicated per dword -> torn-view safe.
__device__ __forceinline__ u64 tmask(int e) {
  int q = (e >> 1) & 3;
  return (u64)(q & 1) * 0x0000400000004000ULL
       | (u64)((q >> 1) & 1) * 0x4000000040000000ULL;
}

struct SMem {
  unsigned short wB[2][4][16][64][8]; // 128 KiB: [whh0|wih1][wave][kc][lane][8]
  u64 a0[16 * 68];                    // 8.5 KiB staged A: [kc][b*8 + k8&7]
  u64 a1[16 * 68];                    // 8.5 KiB
  unsigned short wfc2[1024];          // 2 KiB: W_fc rows w*2, w*2+1 (bf16)
  float gpart[4][272];                // per-wave D staging
  float fcp[256];                     // fc partials
  float b0s[64], b1s[64], b0d[64], bfc2[2];
};                                    // ~153 KiB

// staged-A LDS u64 index for global h u64-index idx (b=idx>>7, k8=idx&127)
__device__ __forceinline__ int amap(int idx) {
  int b = idx >> 7, k8 = idx & 127;
  return (k8 >> 3) * 68 + b * 8 + (k8 & 7);
}

// poll-stage: spin on tagged h entries. All loads of one iteration issued
// back-to-back in ONE asm batch at DEVICE scope (sc1) with a single
// vmcnt(0) wait (rule #18). Verified correct+coherent in R14.
__device__ __forceinline__ void pollstage1(u64* dst, const u64* src, u64 want, int tid) {
  u64 v0, v1, v2, v3;
  const u64* p0 = src + tid;       const u64* p1 = src + tid + 256;
  const u64* p2 = src + tid + 512; const u64* p3 = src + tid + 768;
  int guard = 0;
  while (true) {
    asm volatile(
      "global_load_dwordx2 %0, %4, off sc1\n\t"
      "global_load_dwordx2 %1, %5, off sc1\n\t"
      "global_load_dwordx2 %2, %6, off sc1\n\t"
      "global_load_dwordx2 %3, %7, off sc1\n\t"
      "s_waitcnt vmcnt(0)"
      : "=&v"(v0), "=&v"(v1), "=&v"(v2), "=&v"(v3)
      : "v"(p0), "v"(p1), "v"(p2), "v"(p3)
      : "memory");
    __builtin_amdgcn_sched_barrier(0);
    bool ok = ((v0 & TAGBITS) == want) & ((v1 & TAGBITS) == want) &
              ((v2 & TAGBITS) == want) & ((v3 & TAGBITS) == want);
    if (ok || ++guard > 8192) break;
    __builtin_amdgcn_s_sleep(1);
  }
  dst[amap(tid)]       = v0 & ~TAGBITS; dst[amap(tid + 256)] = v1 & ~TAGBITS;
  dst[amap(tid + 512)] = v2 & ~TAGBITS; dst[amap(tid + 768)] = v3 & ~TAGBITS;
}
__device__ __forceinline__ void pollstage2(u64* d0, const u64* s0, u64 w0,
                                           u64* d1, const u64* s1, u64 w1, int tid) {
  u64 a0, a1, a2, a3, b0, b1, b2, b3;
  const u64* pa0 = s0 + tid;       const u64* pa1 = s0 + tid + 256;
  const u64* pa2 = s0 + tid + 512; const u64* pa3 = s0 + tid + 768;
  const u64* pb0 = s1 + tid;       const u64* pb1 = s1 + tid + 256;
  const u64* pb2 = s1 + tid + 512; const u64* pb3 = s1 + tid + 768;
  int guard = 0;
  while (true) {
    asm volatile(
      "global_load_dwordx2 %0, %8, off sc1\n\t"
      "global_load_dwordx2 %1, %9, off sc1\n\t"
      "global_load_dwordx2 %2, %10, off sc1\n\t"
      "global_load_dwordx2 %3, %11, off sc1\n\t"
      "global_load_dwordx2 %4, %12, off sc1\n\t"
      "global_load_dwordx2 %5, %13, off sc1\n\t"
      "global_load_dwordx2 %6, %14, off sc1\n\t"
      "global_load_dwordx2 %7, %15, off sc1\n\t"
      "s_waitcnt vmcnt(0)"
      : "=&v"(a0), "=&v"(a1), "=&v"(a2), "=&v"(a3),
        "=&v"(b0), "=&v"(b1), "=&v"(b2), "=&v"(b3)
      : "v"(pa0), "v"(pa1), "v"(pa2), "v"(pa3),
        "v"(pb0), "v"(pb1), "v"(pb2), "v"(pb3)
      : "memory");
    __builtin_amdgcn_sched_barrier(0);
    bool ok = ((a0 & TAGBITS) == w0) & ((a1 & TAGBITS) == w0) &
              ((a2 & TAGBITS) == w0) & ((a3 & TAGBITS) == w0) &
              ((b0 & TAGBITS) == w1) & ((b1 & TAGBITS) == w1) &
              ((b2 & TAGBITS) == w1) & ((b3 & TAGBITS) == w1);
    if (ok || ++guard > 8192) break;
    __builtin_amdgcn_s_sleep(1);
  }
  d0[amap(tid)]       = a0 & ~TAGBITS; d0[amap(tid + 256)] = a1 & ~TAGBITS;
  d0[amap(tid + 512)] = a2 & ~TAGBITS; d0[amap(tid + 768)] = a3 & ~TAGBITS;
  d1[amap(tid)]       = b0 & ~TAGBITS; d1[amap(tid + 256)] = b1 & ~TAGBITS;
  d1[amap(tid + 512)] = b2 & ~TAGBITS; d1[amap(tid + 768)] = b3 & ~TAGBITS;
}

#define MFMA(a, b, c) __builtin_amdgcn_mfma_f32_16x16x32_bf16(a, b, c, 0, 0, 0)

__global__ __launch_bounds__(NTH, 1) void lstm_kernel(
    const float* __restrict__ x,
    const float* __restrict__ Wih0, const float* __restrict__ Whh0,
    const float* __restrict__ bih0, const float* __restrict__ bhh0,
    const float* __restrict__ Wih1, const float* __restrict__ Whh1,
    const float* __restrict__ bih1, const float* __restrict__ bhh1,
    const float* __restrict__ Wfc, const float* __restrict__ bfc,
    u64* h0q, u64* h1q, float* __restrict__ out)
{
  __shared__ SMem sm;
  const int g = blockIdx.x & 7;
  const int wgw = blockIdx.x >> 3;
  const int tid = threadIdx.x;

  // ---- weight staging (fragment-major, conflict-free reads) ----
  for (int e = tid; e < 8192; e += NTH) {   // 2 mats x 4 waves x 16 kc x 64 lanes
    int m = e >> 12, w4 = (e >> 10) & 3, kc = (e >> 6) & 15, l = e & 63;
    int colx = l & 15, qx = l >> 4;
    size_t row = (size_t)((colx & 3) * 512 + wgw * 16 + w4 * 4 + (colx >> 2));
    const float* src = (m ? Wih1 : Whh0) + row * 512 + kc * 32 + qx * 8;
    unsigned short* dst = &sm.wB[m][w4][kc][l][0];
    float4 u = *(const float4*)src, v = *(const float4*)(src + 4);
    dst[0] = f2bf(u.x); dst[1] = f2bf(u.y); dst[2] = f2bf(u.z); dst[3] = f2bf(u.w);
    dst[4] = f2bf(v.x); dst[5] = f2bf(v.y); dst[6] = f2bf(v.z); dst[7] = f2bf(v.w);
  }
  for (int e = tid; e < 1024; e += NTH)
    sm.wfc2[e] = f2bf(Wfc[(size_t)(wgw * 2 + (e >> 9)) * 512 + (e & 511)]);
  if (tid < 64) {
    int jj = tid >> 2, g4 = tid & 3;
    int grow = g4 * 512 + wgw * 16 + jj;
    float s0 = bih0[grow] + bhh0[grow];
    sm.b0s[tid] = s0;
    sm.b1s[tid] = bih1[grow] + bhh1[grow];
    float ex = 0.f;                         // Wih0 row dot bfc (decoder bias)
    for (int i = 0; i < 64; ++i) ex += Wih0[(size_t)grow * 64 + i] * bfc[i];
    sm.b0d[tid] = s0 + ex;
  }
  if (tid < 2) sm.bfc2[tid] = bfc[wgw * 2 + tid];

  // ---- per-lane constants ----
  const int wave = tid >> 6, lane = tid & 63;
  const int col = lane & 15, quad = lane >> 4;
  const int koff = quad * 8;
  const size_t rowg = (size_t)((col & 3) * 512 + wgw * 16 + wave * 4 + (col >> 2));

  // ---- register B-fragments: W_hh1, W_ih0, Wcomb = Wih0 @ Wfc ----
  bf16x8 whh1f[16];
#pragma unroll
  for (int kc = 0; kc < 16; ++kc) {
    const float* p = Whh1 + rowg * 512 + kc * 32 + koff;
    float4 u = *(const float4*)p, v = *(const float4*)(p + 4);
    bf16x8 r;
    r[0] = (short)f2bf(u.x); r[1] = (short)f2bf(u.y); r[2] = (short)f2bf(u.z); r[3] = (short)f2bf(u.w);
    r[4] = (short)f2bf(v.x); r[5] = (short)f2bf(v.y); r[6] = (short)f2bf(v.z); r[7] = (short)f2bf(v.w);
    whh1f[kc] = r;
  }
  bf16x8 wih0f[2];
#pragma unroll
  for (int kc = 0; kc < 2; ++kc) {
    const float* p = Wih0 + rowg * 64 + kc * 32 + koff;
    float4 u = *(const float4*)p, v = *(const float4*)(p + 4);
    bf16x8 r;
    r[0] = (short)f2bf(u.x); r[1] = (short)f2bf(u.y); r[2] = (short)f2bf(u.z); r[3] = (short)f2bf(u.w);
    r[4] = (short)f2bf(v.x); r[5] = (short)f2bf(v.y); r[6] = (short)f2bf(v.z); r[7] = (short)f2bf(v.w);
    wih0f[kc] = r;
  }
  bf16x8 wcombf[16];
  {
    float wc[16][8];
#pragma unroll
    for (int kc = 0; kc < 16; ++kc)
#pragma unroll
      for (int j = 0; j < 8; ++j) wc[kc][j] = 0.f;
    for (int i = 0; i < 64; ++i) {
      float wi = Wih0[rowg * 64 + i];
      const float* fr = Wfc + (size_t)i * 512 + koff;
#pragma unroll
      for (int kc = 0; kc < 16; ++kc) {
        float4 u = *(const float4*)(fr + kc * 32);
        float4 v = *(const float4*)(fr + kc * 32 + 4);
        wc[kc][0] += wi * u.x; wc[kc][1] += wi * u.y;
        wc[kc][2] += wi * u.z; wc[kc][3] += wi * u.w;
        wc[kc][4] += wi * v.x; wc[kc][5] += wi * v.y;
        wc[kc][6] += wi * v.z; wc[kc][7] += wi * v.w;
      }
    }
#pragma unroll
    for (int kc = 0; kc < 16; ++kc) {
      bf16x8 r;
#pragma unroll
      for (int j = 0; j < 8; ++j) r[j] = (short)f2bf(wc[kc][j]);
      wcombf[kc] = r;
    }
  }
  __syncthreads();

  const float b0c = sm.b0s[wave * 16 + col];
  const float b1c = sm.b1s[wave * 16 + col];
  const float b0dc = sm.b0d[wave * 16 + col];
  const unsigned short* pw0 = &sm.wB[0][wave][0][lane][0];   // + kc*512 ushort
  const unsigned short* pw1 = &sm.wB[1][wave][0][lane][0];
  const u64* afrag0 = sm.a0 + (col & 7) * 8 + quad * 2;      // + kc*68
  const u64* afrag1 = sm.a1 + (col & 7) * 8 + quad * 2;
  float c0 = 0.f, c1 = 0.f;
  const size_t xstride = (size_t)Tt * 64;

  auto hslot = [&](u64* hq, int e) -> u64* {
    return hq + ((size_t)(e & 1) << 13) + g * 1024;
  };

  auto loadx = [&](const float* p) -> bf16x8 {
    float4 u = *(const float4*)p, v = *(const float4*)(p + 4);
    bf16x8 r;
    r[0] = (short)f2bf(u.x); r[1] = (short)f2bf(u.y); r[2] = (short)f2bf(u.z); r[3] = (short)f2bf(u.w);
    r[4] = (short)f2bf(v.x); r[5] = (short)f2bf(v.y); r[6] = (short)f2bf(v.z); r[7] = (short)f2bf(v.w);
    return r;
  };

  // compute h, publish TAGGED to the epoch slot (agent store, fire-and-forget)
  auto actstore = [&](f32x4 v, float& cst, u64* hdst, u64 tg) {
    float* gp = sm.gpart[wave];
#pragma unroll
    for (int r = 0; r < 4; ++r) gp[(quad * 4 + r) * 17 + col] = v[r];
    unsigned hbits = 0;
    int b = lane >> 2, j = lane & 3;
    if (lane < 32) {
      const float* ro = gp + b * 17 + j * 4;
      float iv = sigm(ro[0]), fv = sigm(ro[1]), gv = tanh_(ro[2]), ov = sigm(ro[3]);
      float c = fv * cst + iv * gv; cst = c;
      hbits = f2bf(ov * tanh_(c));   // |h|<1 -> bit14 == 0 guaranteed
    }
    unsigned h1b = __shfl(hbits, (lane + 1) & 63);
    unsigned h2b = __shfl(hbits, (lane + 2) & 63);
    unsigned h3b = __shfl(hbits, (lane + 3) & 63);
    if (lane < 32 && j == 0) {
      u64 pk = (u64)hbits | ((u64)h1b << 16) | ((u64)h2b << 32) | ((u64)h3b << 48);
      ast64a(hdst + b * 128 + wgw * 4 + wave, pk | tg);
    }
  };

  auto fcpart = [&](const u64* asrc) {      // fc partials from staged h1
    int ks = tid >> 4, b = (tid >> 1) & 7, cc = tid & 1;
    const unsigned short* hr = (const unsigned short*)(asrc + ks * 68 + b * 8);
    const unsigned short* wp = sm.wfc2 + cc * 512 + ks * 32;
    float s = 0.f;
#pragma unroll
    for (int k2 = 0; k2 < 4; ++k2) {
      bf16x8 hv = *(const bf16x8*)(hr + k2 * 8);
      bf16x8 wv = *(const bf16x8*)(wp + k2 * 8);
#pragma unroll
      for (int q2 = 0; q2 < 8; ++q2) s += bf2f((unsigned short)hv[q2]) * bf2f((unsigned short)wv[q2]);
    }
    sm.fcp[tid] = s;
  };
  auto fcout = [&](int d) {                 // reduce + write out[d] (tid<16)
    if (tid < 16) {
      float sv = sm.bfc2[tid & 1];
#pragma unroll
      for (int k = 0; k < 16; ++k) sv += sm.fcp[k * 16 + tid];
      int bb = tid >> 1, cc = tid & 1;
      out[(size_t)(g * 8 + bb) * (TGT * 64) + d * 64 + (wgw * 2 + cc)] = sv;
    }
  };

  // ================= encoder: t = 0..512, layer1 lags by 1 =================
  for (int t = 0; t <= Tt; ++t) {
    bf16x8 xa0, xa1;
    if (t < Tt) {
      const float* xb = x + (size_t)(g * 8 + (col & 7)) * xstride + (size_t)t * 64 + koff;
      xa0 = loadx(xb); xa1 = loadx(xb + 32);
    }
    if (t == 1) {
      __syncthreads();                     // prior-step LDS readers done
      pollstage1(sm.a0, hslot(h0q, 0), tmask(0), tid);
      __syncthreads();
    } else if (t >= 2) {
      __syncthreads();
      pollstage2(sm.a0, hslot(h0q, t - 1), tmask(t - 1),
                 sm.a1, hslot(h1q, t - 2), tmask(t - 2), tid);
      __syncthreads();
    }

    if (t < Tt) {
      f32x4 za = {b0c, b0c, b0c, b0c}, zb = {0.f, 0.f, 0.f, 0.f};
      za = MFMA(xa0, wih0f[0], za);
      zb = MFMA(xa1, wih0f[1], zb);
      if (t >= 1) {
        // ---- layer0 FIRST (the h0 chain), publish h0 EARLY (R12) ----
#pragma unroll
        for (int kc = 0; kc < 16; ++kc) {
          bf16x8 a = *(const bf16x8*)(afrag0 + kc * 68);
          bf16x8 w0 = *(const bf16x8*)(pw0 + kc * 512);
          if (kc & 1) zb = MFMA(a, w0, zb);
          else        za = MFMA(a, w0, za);
        }
        actstore(za + zb, c0, hslot(h0q, t), tmask(t));
        // ---- layer1 second (consumed one phase later; off the h0 chain) --
        f32x4 ya = {b1c, b1c, b1c, b1c}, yb = {0.f, 0.f, 0.f, 0.f};
#pragma unroll
        for (int kc = 0; kc < 16; ++kc) {
          bf16x8 a = *(const bf16x8*)(afrag0 + kc * 68);
          bf16x8 w1 = *(const bf16x8*)(pw1 + kc * 512);
          if (kc & 1) yb = MFMA(a, w1, yb);
          else        ya = MFMA(a, w1, ya);
        }
        if (t >= 2) {
#pragma unroll
          for (int kc = 0; kc < 16; ++kc) {
            bf16x8 a = *(const bf16x8*)(afrag1 + kc * 68);
            if (kc & 1) yb = MFMA(a, whh1f[kc], yb);
            else        ya = MFMA(a, whh1f[kc], ya);
          }
        }
        actstore(ya + yb, c1, hslot(h1q, t - 1), tmask(t - 1));
      } else {
        actstore(za + zb, c0, hslot(h0q, 0), tmask(0));
      }
    } else {                                   // t == Tt: final layer1 step
      f32x4 ya = {b1c, b1c, b1c, b1c}, yb = {0.f, 0.f, 0.f, 0.f};
#pragma unroll
      for (int kc = 0; kc < 16; ++kc) {
        bf16x8 a = *(const bf16x8*)(afrag0 + kc * 68);
        bf16x8 w1 = *(const bf16x8*)(pw1 + kc * 512);
        if (kc & 1) yb = MFMA(a, w1, yb);
        else        ya = MFMA(a, w1, ya);
      }
#pragma unroll
      for (int kc = 0; kc < 16; ++kc) {
        bf16x8 a = *(const bf16x8*)(afrag1 + kc * 68);
        if (kc & 1) yb = MFMA(a, whh1f[kc], yb);
        else        ya = MFMA(a, whh1f[kc], ya);
      }
      actstore(ya + yb, c1, hslot(h1q, Tt - 1), tmask(Tt - 1));
    }
  }

  // ================= decoder (h0 epochs 512+d, h1 epochs 512+d) ============
  // d=0, phase A (real x input):
  {
    __syncthreads();
    pollstage2(sm.a0, hslot(h0q, 511), tmask(511),
               sm.a1, hslot(h1q, 511), tmask(511), tid);
    __syncthreads();
    const float* xb = x + (size_t)(g * 8 + (col & 7)) * xstride + (size_t)(Tt - 1) * 64 + koff;
    bf16x8 xa0 = loadx(xb), xa1 = loadx(xb + 32);
    f32x4 za = {b0c, b0c, b0c, b0c}, zb = {0.f, 0.f, 0.f, 0.f};
    za = MFMA(xa0, wih0f[0], za);
    zb = MFMA(xa1, wih0f[1], zb);
#pragma unroll
    for (int kc = 0; kc < 16; ++kc) {
      bf16x8 a = *(const bf16x8*)(afrag0 + kc * 68);
      bf16x8 w0 = *(const bf16x8*)(pw0 + kc * 512);
      if (kc & 1) zb = MFMA(a, w0, zb);
      else        za = MFMA(a, w0, za);
    }
    actstore(za + zb, c0, hslot(h0q, 512), tmask(512));
  }
  // d=0, phase B (a1 still holds h1_enc_last = epoch 511):
  {
    __syncthreads();
    pollstage1(sm.a0, hslot(h0q, 512), tmask(512), tid);
    __syncthreads();
    f32x4 ya = {b1c, b1c, b1c, b1c}, yb = {0.f, 0.f, 0.f, 0.f};
#pragma unroll
    for (int kc = 0; kc < 16; ++kc) {
      bf16x8 a = *(const bf16x8*)(afrag0 + kc * 68);
      bf16x8 w1 = *(const bf16x8*)(pw1 + kc * 512);
      bf16x8 a2 = *(const bf16x8*)(afrag1 + kc * 68);
      if (kc & 1) { yb = MFMA(a, w1, yb); yb = MFMA(a2, whh1f[kc], yb); }
      else        { ya = MFMA(a, w1, ya); ya = MFMA(a2, whh1f[kc], ya); }
    }
    actstore(ya + yb, c1, hslot(h1q, 512), tmask(512));
  }

  for (int d = 1; d < TGT; ++d) {
    // phase A': layer0 with folded fc feedback (Wcomb); gates+publish FIRST,
    // fc epilogue (out[d-1]) after — off the h0 chain (R12).
    {
      __syncthreads();
      pollstage2(sm.a0, hslot(h0q, 511 + d), tmask(511 + d),
                 sm.a1, hslot(h1q, 511 + d), tmask(511 + d), tid);
      __syncthreads();
      f32x4 za = {b0dc, b0dc, b0dc, b0dc}, zb = {0.f, 0.f, 0.f, 0.f};
#pragma unroll
      for (int kc = 0; kc < 16; ++kc) {
        bf16x8 a = *(const bf16x8*)(afrag0 + kc * 68);
        bf16x8 w0 = *(const bf16x8*)(pw0 + kc * 512);
        bf16x8 a2 = *(const bf16x8*)(afrag1 + kc * 68);
        if (kc & 1) { zb = MFMA(a, w0, zb); zb = MFMA(a2, wcombf[kc], zb); }
        else        { za = MFMA(a, w0, za); za = MFMA(a2, wcombf[kc], za); }
      }
      actstore(za + zb, c0, hslot(h0q, 512 + d), tmask(512 + d));
      fcpart(sm.a1);                                 // y_{d-1} partials (epilogue)
      __syncthreads();
      fcout(d - 1);
    }
    // phase B: layer1 (a1 still holds h1_{d-1})
    {
      __syncthreads();
      pollstage1(sm.a0, hslot(h0q, 512 + d), tmask(512 + d), tid);
      __syncthreads();
      f32x4 ya = {b1c, b1c, b1c, b1c}, yb = {0.f, 0.f, 0.f, 0.f};
#pragma unroll
      for (int kc = 0; kc < 16; ++kc) {
        bf16x8 a = *(const bf16x8*)(afrag0 + kc * 68);
        bf16x8 w1 = *(const bf16x8*)(pw1 + kc * 512);
        bf16x8 a2 = *(const bf16x8*)(afrag1 + kc * 68);
        if (kc & 1) { yb = MFMA(a, w1, yb); yb = MFMA(a2, whh1f[kc], yb); }
        else        { ya = MFMA(a, w1, ya); ya = MFMA(a2, whh1f[kc], ya); }
      }
      actstore(ya + yb, c1, hslot(h1q, 512 + d), tmask(512 + d));
    }
  }

  // final fc: out[95] from h1 epoch 607
  {
    __syncthreads();
    pollstage1(sm.a1, hslot(h1q, 512 + TGT - 1), tmask(512 + TGT - 1), tid);
    __syncthreads();
    fcpart(sm.a1);
    __syncthreads();
    fcout(TGT - 1);
  }
}

extern "C" void kernel_launch(void* const* d_in, const int* in_sizes, int n_in,
                              void* d_out, int out_size, void* d_ws, size_t ws_size,
                              hipStream_t stream) {
  (void)in_sizes; (void)n_in; (void)out_size; (void)ws_size;
  const float* x    = (const float*)d_in[0];
  const float* Wih0 = (const float*)d_in[1];
  const float* Whh0 = (const float*)d_in[2];
  const float* bih0 = (const float*)d_in[3];
  const float* bhh0 = (const float*)d_in[4];
  const float* Wih1 = (const float*)d_in[5];
  const float* Whh1 = (const float*)d_in[6];
  const float* bih1 = (const float*)d_in[7];
  const float* bhh1 = (const float*)d_in[8];
  const float* Wfc  = (const float*)d_in[9];
  const float* bfc  = (const float*)d_in[10];

  char* ws = (char*)d_ws;
  u64* h0q = (u64*)ws;                    // 2 slots x 8192 u64 = 128 KiB
  u64* h1q = (u64*)(ws + 131072);         // 128 KiB

  // 0xFF poison: tag bits all 1 (q=3) -> mismatches the q=0 tags of epochs
  // 0/1, so never-written entries can't be consumed. Total ws use: 256 KiB.
  hipMemsetAsync(ws, 0xFF, 262144, stream);
  hipLaunchKernelGGL(lstm_kernel, dim3(NWG), dim3(NTH), 0, stream,
                     x, Wih0, Whh0, bih0, bhh0, Wih1, Whh1, bih1, bhh1, Wfc, bfc,
                     h0q, h1q, (float*)d_out);
}